// Round 8
// baseline (419.002 us; speedup 1.0000x reference)
//
#include <hip/hip_runtime.h>
#include <cmath>

#define NBATCH 8
#define NCH    256
#define NH     80
#define NW     160
#define NDISP  24
#define FAC    8

constexpr int TPB1  = 256;                     // 4 waves per block
constexpr int WPB   = 4;
constexpr int NTILE = 5;                       // 32-wide w tiles per row
constexpr int SLOTS = 192;                     // per buffer: 128 R-quads + 64 L-quads (float4)
constexpr int NBUF  = 3;                       // 3 rotating buffers (reg-staged)

__device__ __forceinline__ void wait_lgkm0() {
  asm volatile("s_waitcnt lgkmcnt(0)" ::: "memory");
  __builtin_amdgcn_sched_barrier(0);
}

__device__ __forceinline__ float f4c(const float4& v, int k) {
  switch (k) { case 0: return v.x; case 1: return v.y; case 2: return v.z; default: return v.w; }
}

// ---------------- K1: wave-autonomous cost volume + top3 + softmax expectation ----------------
// wave = (row, 32-w tile); lanes = 8wq x 8cg; 32 channels/thread; NO barriers.
// REG-STAGED pipeline: global->VGPR (named X/Y sets, compiler-counted vmcnt) -> ds_write_b128
// (lane-linear, conflict-free) -> 3-buffer rotation -> swizzled ds_read_b128 + FMA.
__global__ __launch_bounds__(TPB1) void cost_topk_kernel(
    const float* __restrict__ left, const float* __restrict__ right,
    float* __restrict__ disp)
{
  __shared__ float4 lds4[WPB][NBUF][SLOTS];    // 36 KB/block, wave-private [widx]

  const int lane = threadIdx.x & 63;
  const int widx = threadIdx.x >> 6;
  const int wid  = blockIdx.x * WPB + widx;    // 0..3199
  const int tile = wid % NTILE;
  const int row  = wid / NTILE;                // b*NH + h
  const int b    = row / NH;
  const int h    = row % NH;
  const int wb   = tile * 32;

  const int cg = lane & 7;
  const int wq = lane >> 3;

  const size_t hw = (size_t)NH * NW;
  const float* lrow = left  + (size_t)b * NCH * hw + (size_t)h * NW;
  const float* rrow = right + (size_t)b * NCH * hw + (size_t)h * NW;

  // staging sources (per lane, channel 0); lane l owns slot l (R0), 64+l (R1), 128+l (L).
  // slot s holds (c,q) with s = c*16 + (q^c) [R] / 128 + c*8 + (wq^c) [L]; invert XOR on source.
  const int c0 = lane >> 4,        q0 = (lane & 15) ^ c0;        // R slots 0..63
  const int c1 = 4 + (lane >> 4),  q1 = (lane & 15) ^ c1;        // R slots 64..127
  const int cl = lane >> 3,        wqs = (lane & 7) ^ cl;        // L slots 128..191

  int off0 = wb - 32 + 4 * q0; if (off0 < 0) off0 = 0;           // clamp (overwritten by apron-zero)
  int off1 = wb - 32 + 4 * q1; if (off1 < 0) off1 = 0;

  const float* srcR0 = rrow + (size_t)(c0 * 32) * hw + off0;
  const float* srcR1 = rrow + (size_t)(c1 * 32) * hw + off1;
  const float* srcL  = lrow + (size_t)(cl * 32) * hw + wb + 4 * wqs;

  float4* const wbase = &lds4[widx][0][0];

  // two named register staging sets (rule #20: no runtime-indexed reg arrays)
  float4 Xr0, Xr1, Xl, Yr0, Yr1, Yl;

#define LOADS(S, CH) do {                                                     \
    S##r0 = *reinterpret_cast<const float4*>(srcR0 + (size_t)(CH) * hw);      \
    S##r1 = *reinterpret_cast<const float4*>(srcR1 + (size_t)(CH) * hw);      \
    S##l  = *reinterpret_cast<const float4*>(srcL  + (size_t)(CH) * hw); } while (0)

#define WRITES(B, S) do {                                                     \
    float4* bw = wbase + (B) * SLOTS;                                         \
    bw[lane] = S##r0; bw[64 + lane] = S##r1; bw[128 + lane] = S##l; } while (0)

  // compute-side swizzled slots (per-thread constants)
  int rsl[7];
#pragma unroll
  for (int k = 0; k < 7; ++k) rsl[k] = cg * 16 + ((wq + 2 + k) ^ cg);
  const int lslot = 128 + cg * 8 + (wq ^ cg);

  float acc[NDISP][4];
#pragma unroll
  for (int i = 0; i < NDISP; ++i)
#pragma unroll
    for (int ws = 0; ws < 4; ++ws) acc[i][ws] = 0.f;

  auto fmastep = [&](const float4* base) {
    float4 Lq = base[lslot];
    float4 Qa = base[rsl[0]];
#pragma unroll
    for (int g = 0; g < 6; ++g) {
      float4 Qb = base[rsl[g + 1]];
      const int i0 = 20 - 4 * g;
#pragma unroll
      for (int di = 0; di < 4; ++di)
#pragma unroll
        for (int ws = 0; ws < 4; ++ws) {
          const int pos = ws - di + 4;               // 1..7 in [Qa|Qb]
          float rv = (pos < 4) ? f4c(Qa, pos) : f4c(Qb, pos - 4);
          acc[i0 + di][ws] = __builtin_fmaf(f4c(Lq, ws), rv, acc[i0 + di][ws]);
        }
      Qa = Qb;
    }
  };

  const float4 fzero{0.f, 0.f, 0.f, 0.f};
  const int azslot = (lane >> 3) * 16 + (lane & 7); // R slots q=0..7 per c (w<0 apron)

  // prologue: fill bufs 0,1 (ch 0,1); issue loads for ch 2,3
  LOADS(X, 0); LOADS(Y, 1);
  WRITES(0, X);                                // compiler inserts counted vmcnt for X here
  LOADS(X, 2);
  WRITES(1, Y);
  LOADS(Y, 3);

  // steady state: at step j {lgkm-guard; write ch j+2 into buf (j+2)%3; load ch j+4; compute buf j%3}
#define STEPJ(J, S) do {                                                      \
    wait_lgkm0();  /* WAR: step J-1's reads of buf (J+2)%3 retired */         \
    if ((J) + 2 < 32) {                                                       \
      WRITES(((J) + 2) % 3, S);                                               \
      if ((J) + 4 < 32) LOADS(S, (J) + 4);                                    \
    }                                                                         \
    __builtin_amdgcn_sched_barrier(0);  /* pin loads before compute */        \
    { float4* bc = wbase + ((J) % 3) * SLOTS;                                 \
      if (tile == 0) bc[azslot] = fzero;                                      \
      fmastep(bc); } } while (0)

#pragma unroll
  for (int jj = 0; jj < 32; jj += 2) {
    STEPJ(jj, X);
    STEPJ(jj + 1, Y);
  }
#undef STEPJ
#undef WRITES
#undef LOADS

  // butterfly reduce over the 8 cg lanes (deterministic symmetric tree)
#pragma unroll
  for (int mskm = 1; mskm < 8; mskm <<= 1)
#pragma unroll
    for (int i = 0; i < NDISP; ++i)
#pragma unroll
      for (int ws = 0; ws < 4; ++ws)
        acc[i][ws] += __shfl_xor(acc[i][ws], mskm, 64);

  if (cg == 0) {
    float o[4];
#pragma unroll
    for (int ws = 0; ws < 4; ++ws) {
      float v1 = -1e30f, v2 = -1e30f, v3 = -1e30f;
      int   j1 = 0, j2 = 0, j3 = 0;
#pragma unroll
      for (int i = 0; i < NDISP; ++i) {
        float v = acc[i][ws] * 0.00390625f;    // mean: exact *2^-8
        if (v > v1)      { v3 = v2; j3 = j2; v2 = v1; j2 = j1; v1 = v; j1 = i; }
        else if (v > v2) { v3 = v2; j3 = j2; v2 = v;  j2 = i; }
        else if (v > v3) { v3 = v;  j3 = i; }
      }
      float e2 = expf(v2 - v1), e3 = expf(v3 - v1);
      float ssum = 1.0f + e2 + e3;
      o[ws] = ((float)j1 + e2 * (float)j2 + e3 * (float)j3) / ssum;
    }
    *reinterpret_cast<float4*>(&disp[((size_t)b * NH + h) * NW + wb + wq * 4]) =
        float4{o[0], o[1], o[2], o[3]};
  }
}

// ---------------- K2: convex upsample, one thread per (b,h,fy,w) -> 8 fx outputs ----------------
__global__ __launch_bounds__(256) void upsample_kernel(
    const float* __restrict__ disp, const float* __restrict__ mask,
    const int* __restrict__ itp, float* __restrict__ out)
{
  int idx = blockIdx.x * 256 + threadIdx.x;    // 8*80*8*160 = 819,200 exactly
  const int w  = idx % NW;
  const int fy = (idx / NW) & 7;
  const int h  = (idx / (NW * FAC)) % NH;
  const int b  = idx / (NW * FAC * NH);

  const float iters = (float)itp[0];
  const float temp  = 1.0f + __expf(-(iters - 1.0f));
  const float sc    = 1.44269504088896340736f / temp;  // log2(e)/temp

  const size_t hw = (size_t)NH * NW;
  const float* drow = disp + (size_t)b * hw;
  float d[9];
#pragma unroll
  for (int dy = 0; dy < 3; ++dy)
#pragma unroll
    for (int dx = 0; dx < 3; ++dx) {
      int h2 = h + dy - 1, w2 = w + dx - 1;
      bool ok = (h2 >= 0) && (h2 < NH) && (w2 >= 0) && (w2 < NW);
      d[dy * 3 + dx] = ok ? drow[h2 * NW + w2] : 0.f;
    }

  const float* mb = mask + (size_t)b * 576 * hw + (size_t)h * NW + w;
  float m[9][FAC];
#pragma unroll
  for (int j = 0; j < 9; ++j)
#pragma unroll
    for (int fx = 0; fx < FAC; ++fx)
      m[j][fx] = mb[(size_t)((j * 8 + fy) * 8 + fx) * hw];

  float o[FAC];
#pragma unroll
  for (int fx = 0; fx < FAC; ++fx) {
    float mx = m[0][fx];
#pragma unroll
    for (int j = 1; j < 9; ++j) mx = fmaxf(mx, m[j][fx]);
    float ssum = 0.f, accv = 0.f;
#pragma unroll
    for (int j = 0; j < 9; ++j) {
      float e = exp2f((m[j][fx] - mx) * sc);
      ssum += e;
      accv += e * d[j];
    }
    o[fx] = (-8.0f * accv) * __builtin_amdgcn_rcpf(ssum);
  }

  float* op = out + ((size_t)b * (NH * FAC) + (size_t)(h * FAC + fy)) * (NW * FAC) + (size_t)w * FAC;
  *reinterpret_cast<float4*>(op)     = float4{o[0], o[1], o[2], o[3]};
  *reinterpret_cast<float4*>(op + 4) = float4{o[4], o[5], o[6], o[7]};
}

extern "C" void kernel_launch(void* const* d_in, const int* in_sizes, int n_in,
                              void* d_out, int out_size, void* d_ws, size_t ws_size,
                              hipStream_t stream) {
  (void)in_sizes; (void)n_in; (void)out_size; (void)ws_size;
  const float* left  = (const float*)d_in[0];
  const float* right = (const float*)d_in[1];
  const float* mask  = (const float*)d_in[2];
  const int*   iters = (const int*)d_in[3];
  float* out  = (float*)d_out;
  float* disp = (float*)d_ws;   // 8*80*160 f32 scratch

  hipLaunchKernelGGL(cost_topk_kernel, dim3(NBATCH * NH * NTILE / WPB), dim3(TPB1), 0, stream,
                     left, right, disp);
  hipLaunchKernelGGL(upsample_kernel, dim3(NBATCH * NH * FAC * NW / 256), dim3(256), 0, stream,
                     disp, mask, iters, out);
}

// Round 9
// 126.659 us; speedup vs baseline: 3.3081x; 3.3081x over previous
//
#include <hip/hip_runtime.h>
#include <cmath>

#define NBATCH 8
#define NCH    256
#define NH     80
#define NW     160
#define NDISP  24
#define FAC    8

constexpr int TPB1  = 256;                     // 4 waves per block
constexpr int WPB   = 4;
constexpr int NTILE = 5;                       // 32-wide w tiles per row
constexpr int SLOTS = 192;                     // per buffer: 128 R-quads + 64 L-quads (float4)
constexpr int NBUF  = 4;                       // depth-4 rotation -> vmcnt(9) steady state

typedef __attribute__((address_space(1))) unsigned int gu32;
typedef __attribute__((address_space(3))) unsigned int lu32;

// aux=2 = NT (gfx94x CPol bit1): stream, don't allocate L2/L3. L/R are read-once per
// dispatch; keeping them out of the caches forces the fast pure-HBM path (K2's regime)
// instead of the slow mixed L3-hit/HBM-miss path. No semantic effect on loads.
#define LDS_AUX 2

__device__ __forceinline__ void gload_lds16(const float* g, float4* l) {
  // one instr: all 64 lanes fetch 16B from per-lane g, HW writes LDS at (uniform l) + lane*16
  __builtin_amdgcn_global_load_lds((gu32*)g, (lu32*)l, 16, 0, LDS_AUX);
}

template <int N>
__device__ __forceinline__ void wait_vm() {
  if constexpr (N == 9)      asm volatile("s_waitcnt vmcnt(9)" ::: "memory");
  else if constexpr (N == 6) asm volatile("s_waitcnt vmcnt(6)" ::: "memory");
  else if constexpr (N == 3) asm volatile("s_waitcnt vmcnt(3)" ::: "memory");
  else                       asm volatile("s_waitcnt vmcnt(0)" ::: "memory");
  __builtin_amdgcn_sched_barrier(0);           // rule #18: pin consumers behind the wait
}

__device__ __forceinline__ void wait_lgkm0() {
  asm volatile("s_waitcnt lgkmcnt(0)" ::: "memory");
  __builtin_amdgcn_sched_barrier(0);
}

__device__ __forceinline__ float f4c(const float4& v, int k) {
  switch (k) { case 0: return v.x; case 1: return v.y; case 2: return v.z; default: return v.w; }
}

// ---------------- K1: wave-autonomous cost volume + top3 + softmax expectation ----------------
// wave = (row, 32-w tile); lanes = 8wq x 8cg; 32 channels/thread; NO barriers.
// Depth-4 LDS pipeline: stage ch j+3 BEFORE waiting/consuming ch j (loads in flight across stalls).
__global__ __launch_bounds__(TPB1) void cost_topk_kernel(
    const float* __restrict__ left, const float* __restrict__ right,
    float* __restrict__ disp)
{
  __shared__ float4 lds4[WPB][NBUF][SLOTS];    // 48 KB/block, wave-private [widx]

  const int lane = threadIdx.x & 63;
  const int widx = threadIdx.x >> 6;
  const int wid  = blockIdx.x * WPB + widx;    // 0..3199
  const int tile = wid % NTILE;
  const int row  = wid / NTILE;                // b*NH + h
  const int b    = row / NH;
  const int h    = row % NH;
  const int wb   = tile * 32;

  const int cg = lane & 7;
  const int wq = lane >> 3;

  const size_t hw = (size_t)NH * NW;
  const float* lrow = left  + (size_t)b * NCH * hw + (size_t)h * NW;
  const float* rrow = right + (size_t)b * NCH * hw + (size_t)h * NW;

  // staging sources (per lane, channel 0); slot s holds (c,q) with s = c*16 + (q^c)  [R]
  // or s = 128 + c*8 + (wq^c) [L]; lane l stages slot l -> invert the XOR on the source side.
  const int c0 = lane >> 4,        q0 = (lane & 15) ^ c0;        // R slots 0..63
  const int c1 = 4 + (lane >> 4),  q1 = (lane & 15) ^ c1;        // R slots 64..127
  const int cl = lane >> 3,        wqs = (lane & 7) ^ cl;        // L slots 128..191

  int off0 = wb - 32 + 4 * q0; if (off0 < 0) off0 = 0;           // clamp (overwritten by apron-zero)
  int off1 = wb - 32 + 4 * q1; if (off1 < 0) off1 = 0;

  const float* srcR0 = rrow + (size_t)(c0 * 32) * hw + off0;
  const float* srcR1 = rrow + (size_t)(c1 * 32) * hw + off1;
  const float* srcL  = lrow + (size_t)(cl * 32) * hw + wb + 4 * wqs;

  float4* const wbase = &lds4[widx][0][0];

#define STAGE(BP) do {                               \
    gload_lds16(srcR0, (BP));                        \
    gload_lds16(srcR1, (BP) + 64);                   \
    gload_lds16(srcL,  (BP) + 128);                  \
    srcR0 += hw; srcR1 += hw; srcL += hw; } while (0)

  // compute-side swizzled slots (per-thread constants)
  int rsl[7];
#pragma unroll
  for (int k = 0; k < 7; ++k) rsl[k] = cg * 16 + ((wq + 2 + k) ^ cg);
  const int lslot = 128 + cg * 8 + (wq ^ cg);

  float acc[NDISP][4];
#pragma unroll
  for (int i = 0; i < NDISP; ++i)
#pragma unroll
    for (int ws = 0; ws < 4; ++ws) acc[i][ws] = 0.f;

  auto fmastep = [&](const float4* base) {
    float4 Lq = base[lslot];
    float4 Qa = base[rsl[0]];
#pragma unroll
    for (int g = 0; g < 6; ++g) {
      float4 Qb = base[rsl[g + 1]];
      const int i0 = 20 - 4 * g;
#pragma unroll
      for (int di = 0; di < 4; ++di)
#pragma unroll
        for (int ws = 0; ws < 4; ++ws) {
          const int pos = ws - di + 4;               // 1..7 in [Qa|Qb]
          float rv = (pos < 4) ? f4c(Qa, pos) : f4c(Qb, pos - 4);
          acc[i0 + di][ws] = __builtin_fmaf(f4c(Lq, ws), rv, acc[i0 + di][ws]);
        }
      Qa = Qb;
    }
  };

  const float4 fzero{0.f, 0.f, 0.f, 0.f};
  const int azslot = (lane >> 3) * 16 + (lane & 7); // R slots q=0..7 per c (w<0 apron)

  // prologue: channels 0,1,2 into buffers 0,1,2 (9 loads in flight)
  STAGE(wbase + 0 * SLOTS);
  STAGE(wbase + 1 * SLOTS);
  STAGE(wbase + 2 * SLOTS);

  // steady state: at step j, stage ch j+3 into buf (j+3)&3 BEFORE consuming buf j&3
#pragma unroll 4
  for (int j = 0; j < 28; ++j) {
    float4* bs = wbase + ((j + 3) & 3) * SLOTS;
    float4* bc = wbase + (j & 3) * SLOTS;
    wait_lgkm0();                                // WAR guard: step j-1's reads of buf (j+3)&3 done
    STAGE(bs);
    wait_vm<9>();                                // buf j's 3 loads retired (12 - 9)
    if (tile == 0) bc[azslot] = fzero;
    fmastep(bc);
  }
  {                                              // j = 28: stages ch 31 (last)
    float4* bs = wbase + 3 * SLOTS;
    float4* bc = wbase + 0 * SLOTS;
    wait_lgkm0(); STAGE(bs); wait_vm<9>();
    if (tile == 0) bc[azslot] = fzero;
    fmastep(bc);
  }
  { float4* bc = wbase + 1 * SLOTS; wait_vm<6>(); if (tile == 0) bc[azslot] = fzero; fmastep(bc); }
  { float4* bc = wbase + 2 * SLOTS; wait_vm<3>(); if (tile == 0) bc[azslot] = fzero; fmastep(bc); }
  { float4* bc = wbase + 3 * SLOTS; wait_vm<0>(); if (tile == 0) bc[azslot] = fzero; fmastep(bc); }
#undef STAGE

  // butterfly reduce over the 8 cg lanes (deterministic symmetric tree)
#pragma unroll
  for (int mskm = 1; mskm < 8; mskm <<= 1)
#pragma unroll
    for (int i = 0; i < NDISP; ++i)
#pragma unroll
      for (int ws = 0; ws < 4; ++ws)
        acc[i][ws] += __shfl_xor(acc[i][ws], mskm, 64);

  if (cg == 0) {
    float o[4];
#pragma unroll
    for (int ws = 0; ws < 4; ++ws) {
      float v1 = -1e30f, v2 = -1e30f, v3 = -1e30f;
      int   j1 = 0, j2 = 0, j3 = 0;
#pragma unroll
      for (int i = 0; i < NDISP; ++i) {
        float v = acc[i][ws] * 0.00390625f;    // mean: exact *2^-8
        if (v > v1)      { v3 = v2; j3 = j2; v2 = v1; j2 = j1; v1 = v; j1 = i; }
        else if (v > v2) { v3 = v2; j3 = j2; v2 = v;  j2 = i; }
        else if (v > v3) { v3 = v;  j3 = i; }
      }
      float e2 = expf(v2 - v1), e3 = expf(v3 - v1);
      float ssum = 1.0f + e2 + e3;
      o[ws] = ((float)j1 + e2 * (float)j2 + e3 * (float)j3) / ssum;
    }
    *reinterpret_cast<float4*>(&disp[((size_t)b * NH + h) * NW + wb + wq * 4]) =
        float4{o[0], o[1], o[2], o[3]};
  }
}

// ---------------- K2: convex upsample, one thread per (b,h,fy,w) -> 8 fx outputs ----------------
__global__ __launch_bounds__(256) void upsample_kernel(
    const float* __restrict__ disp, const float* __restrict__ mask,
    const int* __restrict__ itp, float* __restrict__ out)
{
  int idx = blockIdx.x * 256 + threadIdx.x;    // 8*80*8*160 = 819,200 exactly
  const int w  = idx % NW;
  const int fy = (idx / NW) & 7;
  const int h  = (idx / (NW * FAC)) % NH;
  const int b  = idx / (NW * FAC * NH);

  const float iters = (float)itp[0];
  const float temp  = 1.0f + __expf(-(iters - 1.0f));
  const float sc    = 1.44269504088896340736f / temp;  // log2(e)/temp

  const size_t hw = (size_t)NH * NW;
  const float* drow = disp + (size_t)b * hw;
  float d[9];
#pragma unroll
  for (int dy = 0; dy < 3; ++dy)
#pragma unroll
    for (int dx = 0; dx < 3; ++dx) {
      int h2 = h + dy - 1, w2 = w + dx - 1;
      bool ok = (h2 >= 0) && (h2 < NH) && (w2 >= 0) && (w2 < NW);
      d[dy * 3 + dx] = ok ? drow[h2 * NW + w2] : 0.f;
    }

  const float* mb = mask + (size_t)b * 576 * hw + (size_t)h * NW + w;
  float m[9][FAC];
#pragma unroll
  for (int j = 0; j < 9; ++j)
#pragma unroll
    for (int fx = 0; fx < FAC; ++fx)
      m[j][fx] = mb[(size_t)((j * 8 + fy) * 8 + fx) * hw];

  float o[FAC];
#pragma unroll
  for (int fx = 0; fx < FAC; ++fx) {
    float mx = m[0][fx];
#pragma unroll
    for (int j = 1; j < 9; ++j) mx = fmaxf(mx, m[j][fx]);
    float ssum = 0.f, accv = 0.f;
#pragma unroll
    for (int j = 0; j < 9; ++j) {
      float e = exp2f((m[j][fx] - mx) * sc);
      ssum += e;
      accv += e * d[j];
    }
    o[fx] = (-8.0f * accv) * __builtin_amdgcn_rcpf(ssum);
  }

  float* op = out + ((size_t)b * (NH * FAC) + (size_t)(h * FAC + fy)) * (NW * FAC) + (size_t)w * FAC;
  *reinterpret_cast<float4*>(op)     = float4{o[0], o[1], o[2], o[3]};
  *reinterpret_cast<float4*>(op + 4) = float4{o[4], o[5], o[6], o[7]};
}

extern "C" void kernel_launch(void* const* d_in, const int* in_sizes, int n_in,
                              void* d_out, int out_size, void* d_ws, size_t ws_size,
                              hipStream_t stream) {
  (void)in_sizes; (void)n_in; (void)out_size; (void)ws_size;
  const float* left  = (const float*)d_in[0];
  const float* right = (const float*)d_in[1];
  const float* mask  = (const float*)d_in[2];
  const int*   iters = (const int*)d_in[3];
  float* out  = (float*)d_out;
  float* disp = (float*)d_ws;   // 8*80*160 f32 scratch

  hipLaunchKernelGGL(cost_topk_kernel, dim3(NBATCH * NH * NTILE / WPB), dim3(TPB1), 0, stream,
                     left, right, disp);
  hipLaunchKernelGGL(upsample_kernel, dim3(NBATCH * NH * FAC * NW / 256), dim3(256), 0, stream,
                     disp, mask, iters, out);
}